// Round 17
// baseline (3213.179 us; speedup 1.0000x reference)
//
#include <hip/hip_runtime.h>
#include <hip/hip_bf16.h>
#include <cstdio>

typedef __hip_bfloat16 bf16;
typedef __attribute__((ext_vector_type(8))) short short8v;
typedef __attribute__((ext_vector_type(4))) float f32x4;

#define T_WIN 1993      // N_WINDOWS
#define NSER 512
#define NTIME 2048
#define NGRP 32
#define FLAGS_INTS (4*8*NGRP)

#define WAIT_LGKM0 0xC07F   // lgkmcnt(0) only
#define WAIT_VM0   0x0F70   // vmcnt(0) only

#define SMEM_USHORTS 2304   // hbuf: 2 × 16×72 ushorts (4608 B)

__device__ __forceinline__ float sigmf(float x) { return __fdividef(1.f, 1.f + __expf(-x)); }
__device__ __forceinline__ float tanhf_fast(float x) { return 1.f - __fdividef(2.f, __expf(2.f*x) + 1.f); }
__device__ __forceinline__ ushort f2bfu(float f) {
  __hip_bfloat16 h = __float2bfloat16(f);
  return *reinterpret_cast<ushort*>(&h);
}
__device__ __forceinline__ float bfu2f(ushort u) {
  uint x = ((uint)u) << 16;
  return __uint_as_float(x);
}

// ---------------- y[s][t] -> yT[t][s] (LDS-tiled, conflict-free) -----------
__global__ __launch_bounds__(256) void transpose_y(const float* __restrict__ y,
                                                   float* __restrict__ yT) {
  __shared__ float tile[64][65];
  const int i  = threadIdx.x;
  const int c  = i & 63;
  const int r4 = i >> 6;
  const int t0 = (blockIdx.x & 31) * 64;
  const int s0 = (blockIdx.x >> 5) * 64;
  #pragma unroll
  for (int q = 0; q < 16; ++q) {
    const int sl = q*4 + r4;
    tile[c][sl] = y[(size_t)(s0 + sl)*NTIME + t0 + c];
  }
  __syncthreads();
  #pragma unroll
  for (int q = 0; q < 16; ++q) {
    const int tl = q*4 + r4;
    yT[(size_t)(t0 + tl)*NSER + s0 + c] = tile[tl][c];
  }
}

// ---------------- ES scan (transposed; 8 blocks x 64 -> 8 CUs of BW) -------
__global__ __launch_bounds__(64) void es_kernel_t(const float* __restrict__ yT, const int* __restrict__ idxs,
                            const float* __restrict__ lev_sms, const float* __restrict__ seas_sms,
                            const float* __restrict__ init_seas,
                            float* __restrict__ levT, float* __restrict__ seasT) {
  int s = blockIdx.x*64 + threadIdx.x;
  if (s >= NSER) return;
  int id = idxs[s];
  float ls = sigmf(lev_sms[id]);
  float ss = sigmf(seas_sms[id]);
  float buf[8];
  #pragma unroll
  for (int k=0;k<7;++k) buf[k] = __expf(init_seas[id*7+k]);
  buf[7] = buf[0];
  float lev = __fdividef(yT[s], buf[0]);
  levT[s] = lev;
  #pragma unroll
  for (int t=0;t<8;++t) seasT[t*NSER + s] = buf[t];
  #pragma unroll 8
  for (int t=1;t<NTIME;++t) {
    float yt = yT[t*NSER + s];
    float st = buf[1];
    lev = ls*__fdividef(yt,st) + (1.f-ls)*lev;
    float ns = ss*__fdividef(yt,lev) + (1.f-ss)*st;
    #pragma unroll
    for (int k=0;k<7;++k) buf[k] = buf[k+1];
    buf[7] = ns;
    levT[t*NSER + s] = lev;
    if (t+7 < NTIME) seasT[(t+7)*NSER + s] = ns;
  }
}

// ------- transpose back + fused logs: out_lev/lnorm/llev in [s][t] ---------
__global__ __launch_bounds__(256) void trlog_kernel(const float* __restrict__ y,
        const float* __restrict__ levT, const float* __restrict__ seasT,
        float* __restrict__ out_lev, float* __restrict__ lnorm, float* __restrict__ llev) {
  __shared__ float tl[64][65];
  __shared__ float ts[64][65];
  const int i  = threadIdx.x;
  const int c  = i & 63;
  const int r4 = i >> 6;
  const int t0 = (blockIdx.x & 31) * 64;
  const int s0 = (blockIdx.x >> 5) * 64;
  #pragma unroll
  for (int q = 0; q < 16; ++q) {
    const int tl_ = q*4 + r4;
    const size_t src = (size_t)(t0 + tl_)*NSER + s0 + c;
    tl[tl_][c] = levT[src];
    ts[tl_][c] = seasT[src];
  }
  __syncthreads();
  #pragma unroll
  for (int q = 0; q < 16; ++q) {
    const int sl = q*4 + r4;
    const size_t o = (size_t)(s0 + sl)*NTIME + t0 + c;
    const float lv = tl[c][sl];
    const float sv = ts[c][sl];
    out_lev[o] = lv;
    llev[o]    = __logf(lv);
    lnorm[o]   = __logf(__fdividef(y[o], sv));
  }
}

// ------- windows: xhat ONLY (wy moved into L4 of lstm_fused) ---------------
__global__ __launch_bounds__(256) void window_kernel(const float* __restrict__ lnorm,
                              const float* __restrict__ llev,
                              const float* __restrict__ noise,
                              ushort* __restrict__ xhat) {
  const int NQ = (T_WIN*512*28)/4;
  const int nth = gridDim.x * 256;
  for (int e = blockIdx.x*256 + threadIdx.x; e < NQ; e += nth) {
    const int k4 = (e % 7) * 4;
    const int rs = e / 7;
    const int s  = rs & 511;
    const int w  = rs >> 9;
    const float lv = llev[s*NTIME + 28 + w];
    const float* Ln = lnorm + (size_t)s*NTIME + w + k4;
    const float4 nz = *reinterpret_cast<const float4*>(noise + (size_t)e*4);
    ushort4 xv;
    xv.x = f2bfu(Ln[0] - lv + 0.001f*nz.x);
    xv.y = f2bfu(Ln[1] - lv + 0.001f*nz.y);
    xv.z = f2bfu(Ln[2] - lv + 0.001f*nz.z);
    xv.w = f2bfu(Ln[3] - lv + 0.001f*nz.w);
    *reinterpret_cast<ushort4*>(xhat + (size_t)e*4) = xv;
  }
}

// ---------------- fused 4-layer pipelined LSTM scan (production) -----------
// r17: EPILOGUE FOLDED INTO L4 (8x wall slack: consumes h3 at L1 rate but
// steps at RATE=8). Per L4 step, off-chain: (a) adapter out=(h4+h2)@adW^T+adb
// via 8 MFMAs reusing hf0/hf1 (lagged h4 tile already in regs) + h2 frag
// loads; (b) wy rows from lnorm/llev; (c) h4 global stores DELETED.
// L4 never drains vmcnt in-loop, so added VMEM slides across steps.
template<int KXS, int LAYER>
__device__ __forceinline__ void lstm_scan(
    ushort* __restrict__ hb,
    const ushort* __restrict__ xin, ushort* __restrict__ hout,
    const float* __restrict__ Wih, const float* __restrict__ Whh,
    const float* __restrict__ bih, const float* __restrict__ bhh,
    const int j, const int g, int* __restrict__ flags,
    const float* __restrict__ lnorm, const float* __restrict__ llev,
    const float* __restrict__ adW, const float* __restrict__ adb,
    const ushort* __restrict__ h2g, float* __restrict__ wy, float* __restrict__ yhat)
{
  constexpr int KST  = KXS + 2;
  constexpr int D    = (KXS == 1) ? 28 : 64;
  constexpr int KX   = KXS * 32;
  constexpr int RATE = 1 << LAYER;
  constexpr int SRCR = (LAYER > 0) ? (RATE >> 1) : 1;

  const int i    = threadIdx.x;
  const int lane = i & 63;
  const int wid  = i >> 6;
  const int n15  = lane & 15;
  const int kq   = lane >> 4;
  const int base = g * 16;
  const int wm   = i >> 4;
  const int wu   = (i & 15) * 4;
  const uint km  = (kq == 3) ? 0u : ~0u;

  short8v wfrag[4][KST];
  float bias[4];
  #pragma unroll
  for (int gg = 0; gg < 4; ++gg) {
    const int R = gg*64 + wid*16 + n15;
    bias[gg] = bih[R] + bhh[R];
    #pragma unroll
    for (int kk = 0; kk < KST; ++kk) {
      #pragma unroll
      for (int jj = 0; jj < 8; ++jj) {
        const int k = kk*32 + kq*8 + jj;
        float v;
        if (k < KX) v = (k < D) ? Wih[R*D + k] : 0.f;
        else        v = Whh[R*64 + (k - KX)];
        wfrag[gg][kk][jj] = (short)f2bfu(v);
      }
    }
  }
  f32x4 biasv[4];
  #pragma unroll
  for (int gg = 0; gg < 4; ++gg)
    biasv[gg] = (f32x4){bias[gg], bias[gg], bias[gg], bias[gg]};
  const f32x4 zv = (f32x4){0.f, 0.f, 0.f, 0.f};

  // ---- L4-only: adapter weight fragments + wy thread mapping ----
  short8v adf[2][2];
  f32x4 adbv0 = zv, adbv1 = zv;
  int wy_s0 = 0, wy_k0 = 0, wy_s1 = 0, wy_k1 = 0;
  if constexpr (LAYER == 3) {
    #pragma unroll
    for (int c2 = 0; c2 < 2; ++c2) {
      const int o = c2*16 + n15;
      #pragma unroll
      for (int kk = 0; kk < 2; ++kk)
        #pragma unroll
        for (int jj = 0; jj < 8; ++jj)
          adf[c2][kk][jj] = (o < 28) ? (short)f2bfu(adW[o*64 + kk*32 + kq*8 + jj]) : (short)0;
    }
    const float a0 = adb[n15];
    const float a1 = (16 + n15 < 28) ? adb[16 + n15] : 0.f;
    adbv0 = (f32x4){a0, a0, a0, a0};
    adbv1 = (f32x4){a1, a1, a1, a1};
    wy_s0 = i / 28;        wy_k0 = i - wy_s0*28;
    wy_s1 = (i+256) / 28;  wy_k1 = (i+256) - wy_s1*28;
  }

  for (int e = i; e < 1152; e += 256) hb[e] = 0;
  __syncthreads();

  const int nsteps = (T_WIN - 1 - j)/RATE + 1;
  const int u = wid*16 + n15;
  float cc[4] = {0.f, 0.f, 0.f, 0.f};

  int* myflag = &flags[(LAYER*8 + j)*NGRP + g];
  int* fp = nullptr;
  int seen0 = 0;
  int prodmax = 0x7fffffff;
  if constexpr (LAYER > 0) {
    const int pp0 = j % SRCR;
    fp = &flags[((LAYER-1)*8 + pp0)*NGRP + g];
    prodmax = (T_WIN - 1 - pp0)/SRCR + 1;
  }

  auto wait_for = [&](int t) __attribute__((always_inline)) {
    if constexpr (LAYER > 0) {
      const int tc = (t < T_WIN) ? t : (T_WIN - 1);
      int need = tc/SRCR + 1;
      need = (need < prodmax) ? need : prodmax;
      if (seen0 >= need) return;
      while (__hip_atomic_load(fp, __ATOMIC_RELAXED, __HIP_MEMORY_SCOPE_AGENT) < need)
        __builtin_amdgcn_s_sleep(8);
      seen0 = __hip_atomic_load(fp, __ATOMIC_ACQUIRE, __HIP_MEMORY_SCOPE_AGENT);
    }
  };

  auto loadx = [&](int t, short8v* xf) __attribute__((always_inline)) {
    const int tc = (t < T_WIN) ? t : (T_WIN - 1);
    const ushort* p = xin + ((size_t)tc*512 + base + n15)*(size_t)D + kq*8;
    if constexpr (D == 64) {
      xf[0] = *reinterpret_cast<const short8v*>(p);
      xf[1] = *reinterpret_cast<const short8v*>(p + 32);
    } else {
      ushort4 a = *reinterpret_cast<const ushort4*>(p);
      ushort4 b = *reinterpret_cast<const ushort4*>(p + 4);
      short8v r;
      r[0]=(short)a.x; r[1]=(short)a.y; r[2]=(short)a.z; r[3]=(short)a.w;
      r[4]=(short)(ushort)(b.x & km); r[5]=(short)(ushort)(b.y & km);
      r[6]=(short)(ushort)(b.z & km); r[7]=(short)(ushort)(b.w & km);
      xf[0] = r;
    }
  };

  auto xmm = [&](const short8v* xf, f32x4* xa) __attribute__((always_inline)) {
    #pragma unroll
    for (int gg = 0; gg < 4; ++gg) {
      f32x4 t = __builtin_amdgcn_mfma_f32_16x16x32_bf16(xf[0], wfrag[gg][0], biasv[gg], 0, 0, 0);
      if constexpr (KXS == 2)
        t = __builtin_amdgcn_mfma_f32_16x16x32_bf16(xf[1], wfrag[gg][1], t, 0, 0, 0);
      xa[gg] = t;
    }
  };

  // L4 adapter for time tau from h-fragments (hf0/hf1 = h4[tau] tile)
  auto adapt = [&](int tau, short8v hf0, short8v hf1) __attribute__((always_inline)) {
    const ushort* p2 = h2g + ((size_t)tau*512 + base + n15)*64 + kq*8;
    short8v g0 = *reinterpret_cast<const short8v*>(p2);
    short8v g1 = *reinterpret_cast<const short8v*>(p2 + 32);
    f32x4 c0 = __builtin_amdgcn_mfma_f32_16x16x32_bf16(g0,  adf[0][0], adbv0, 0, 0, 0);
    c0       = __builtin_amdgcn_mfma_f32_16x16x32_bf16(g1,  adf[0][1], c0,    0, 0, 0);
    c0       = __builtin_amdgcn_mfma_f32_16x16x32_bf16(hf0, adf[0][0], c0,    0, 0, 0);
    c0       = __builtin_amdgcn_mfma_f32_16x16x32_bf16(hf1, adf[0][1], c0,    0, 0, 0);
    f32x4 c1 = __builtin_amdgcn_mfma_f32_16x16x32_bf16(g0,  adf[1][0], adbv1, 0, 0, 0);
    c1       = __builtin_amdgcn_mfma_f32_16x16x32_bf16(g1,  adf[1][1], c1,    0, 0, 0);
    c1       = __builtin_amdgcn_mfma_f32_16x16x32_bf16(hf0, adf[1][0], c1,    0, 0, 0);
    c1       = __builtin_amdgcn_mfma_f32_16x16x32_bf16(hf1, adf[1][1], c1,    0, 0, 0);
    #pragma unroll
    for (int r = 0; r < 4; ++r) {
      const size_t row = ((size_t)tau*512 + base + kq*4 + r)*28;
      yhat[row + n15] = c0[r];
      if (n15 < 12) yhat[row + 16 + n15] = c1[r];
    }
  };

  auto stepc = [&](int S, const f32x4* xaC, f32x4* xaN, short8v* xfN, int tN,
                   uint2* hv, bool doNext, bool doAd) __attribute__((always_inline)) {
    const int p_ = S & 1;
    const int t_ = j + S*RATE;
    const ushort* hbp = hb + p_*1152;
    short8v hf0 = *reinterpret_cast<const short8v*>(hbp + n15*72 + kq*8);
    short8v hf1 = *reinterpret_cast<const short8v*>(hbp + n15*72 + 32 + kq*8);
    if constexpr (LAYER != 3) *hv = *reinterpret_cast<const uint2*>(hbp + wm*72 + wu);
    f32x4 A0 = __builtin_amdgcn_mfma_f32_16x16x32_bf16(hf0, wfrag[0][KXS], xaC[0], 0, 0, 0);
    f32x4 A1 = __builtin_amdgcn_mfma_f32_16x16x32_bf16(hf0, wfrag[1][KXS], xaC[1], 0, 0, 0);
    f32x4 A2 = __builtin_amdgcn_mfma_f32_16x16x32_bf16(hf0, wfrag[2][KXS], xaC[2], 0, 0, 0);
    f32x4 A3 = __builtin_amdgcn_mfma_f32_16x16x32_bf16(hf0, wfrag[3][KXS], xaC[3], 0, 0, 0);
    f32x4 B0 = __builtin_amdgcn_mfma_f32_16x16x32_bf16(hf1, wfrag[0][KXS+1], zv, 0, 0, 0);
    f32x4 B1 = __builtin_amdgcn_mfma_f32_16x16x32_bf16(hf1, wfrag[1][KXS+1], zv, 0, 0, 0);
    f32x4 B2 = __builtin_amdgcn_mfma_f32_16x16x32_bf16(hf1, wfrag[2][KXS+1], zv, 0, 0, 0);
    f32x4 B3 = __builtin_amdgcn_mfma_f32_16x16x32_bf16(hf1, wfrag[3][KXS+1], zv, 0, 0, 0);
    if (doNext) {
      xmm(xfN, xaN);
      loadx(tN, xfN);
    }
    if constexpr (LAYER == 3) {
      // wy rows for current t_ (h-independent)
      {
        const float lv0 = llev[(base + wy_s0)*NTIME + 28 + t_];
        wy[((size_t)t_*512 + base + wy_s0)*28 + wy_k0] =
            lnorm[(base + wy_s0)*NTIME + t_ + 28 + wy_k0] - lv0;
        if (i < 192) {
          const float lv1 = llev[(base + wy_s1)*NTIME + 28 + t_];
          wy[((size_t)t_*512 + base + wy_s1)*28 + wy_k1] =
              lnorm[(base + wy_s1)*NTIME + t_ + 28 + wy_k1] - lv1;
        }
      }
      if (doAd) adapt(t_ - RATE, hf0, hf1);   // hf = h4[t_-RATE]
    }
    ushort* hbn = hb + (p_^1)*1152;
    #pragma unroll
    for (int r = 0; r < 4; ++r) {
      const float zi = A0[r] + B0[r];
      const float zf = A1[r] + B1[r];
      const float zg = A2[r] + B2[r];
      const float zo = A3[r] + B3[r];
      cc[r] = sigmf(zf)*cc[r] + sigmf(zi)*tanhf_fast(zg);
      const float h_ = sigmf(zo)*tanhf_fast(cc[r]);
      hbn[(kq*4 + r)*72 + u] = f2bfu(h_);
    }
    __builtin_amdgcn_sched_barrier(0);
    __builtin_amdgcn_s_waitcnt(WAIT_LGKM0);
    __builtin_amdgcn_sched_barrier(0);
    __builtin_amdgcn_s_barrier();
  };

  auto sth = [&](int t, uint2 hv) __attribute__((always_inline)) {
    if constexpr (LAYER != 3)
      *reinterpret_cast<uint2*>(&hout[((size_t)t*512 + base + wm)*64 + wu]) = hv;
  };

  short8v xf0[KXS], xf1[KXS], xf2[KXS], xf3[KXS];
  f32x4 xaP[4], xaQ[4];
  uint2 hh0, hh1, hh2, hh3;

  wait_for(j + 8*RATE);
  loadx(j, xf0);
  xmm(xf0, xaP);
  loadx(j + 4*RATE, xf0);
  loadx(j +   RATE, xf1);
  loadx(j + 2*RATE, xf2);
  loadx(j + 3*RATE, xf3);

  stepc(0, xaP, xaQ, xf1, j + 5*RATE, &hh0, true, false);
  stepc(1, xaQ, xaP, xf2, j + 6*RATE, &hh1, true, true);
  stepc(2, xaP, xaQ, xf3, j + 7*RATE, &hh2, true, true);
  stepc(3, xaQ, xaP, xf0, j + 8*RATE, &hh3, true, true);
  sth(j,          hh1);
  sth(j +   RATE, hh2);
  sth(j + 2*RATE, hh3);

  int B = 4;
  for (; B + 4 <= nsteps; B += 4) {
    wait_for(j + (B + 8)*RATE);
    stepc(B+0, xaP, xaQ, xf1, j + (B+5)*RATE, &hh0, true, true);
    stepc(B+1, xaQ, xaP, xf2, j + (B+6)*RATE, &hh1, true, true);
    stepc(B+2, xaP, xaQ, xf3, j + (B+7)*RATE, &hh2, true, true);
    stepc(B+3, xaQ, xaP, xf0, j + (B+8)*RATE, &hh3, true, true);
    sth(j + (B-1)*RATE, hh0);
    sth(j + (B  )*RATE, hh1);
    sth(j + (B+1)*RATE, hh2);
    sth(j + (B+2)*RATE, hh3);
    if constexpr (LAYER < 3) {
      if ((B & 7) == 4) {
        __builtin_amdgcn_s_waitcnt(WAIT_VM0);
        __builtin_amdgcn_s_barrier();
        if (i == 0)
          __hip_atomic_store(myflag, B+3, __ATOMIC_RELEASE, __HIP_MEMORY_SCOPE_AGENT);
      }
    }
  }
  for (; B < nsteps; ++B) {
    uint2 hvT;
    if (B & 1) stepc(B, xaQ, nullptr, nullptr, 0, &hvT, false, true);
    else       stepc(B, xaP, nullptr, nullptr, 0, &hvT, false, true);
    sth(j + (B-1)*RATE, hvT);
  }

  // final h: store (L<3) or adapter (L4)
  {
    const int pF = nsteps & 1;
    const int tF = j + (nsteps - 1)*RATE;
    if constexpr (LAYER != 3) {
      uint2 hv = *reinterpret_cast<const uint2*>(hb + pF*1152 + wm*72 + wu);
      sth(tF, hv);
    } else {
      const ushort* hbp = hb + pF*1152;
      short8v hf0 = *reinterpret_cast<const short8v*>(hbp + n15*72 + kq*8);
      short8v hf1 = *reinterpret_cast<const short8v*>(hbp + n15*72 + 32 + kq*8);
      adapt(tF, hf0, hf1);
    }
  }
  if constexpr (LAYER < 3) {
    __builtin_amdgcn_s_waitcnt(WAIT_VM0);
    __builtin_amdgcn_s_barrier();
    if (i == 0)
      __hip_atomic_store(myflag, nsteps, __ATOMIC_RELEASE, __HIP_MEMORY_SCOPE_AGENT);
  }
}

__global__ __launch_bounds__(256, 2)
void lstm_fused(const ushort* __restrict__ xhat,
                ushort* __restrict__ h1, ushort* __restrict__ h2,
                const float* __restrict__ Wih0, const float* __restrict__ Wih_rest,
                const float* __restrict__ Whh_all,
                const float* __restrict__ bih_all, const float* __restrict__ bhh_all,
                int* __restrict__ flags,
                const float* __restrict__ lnorm, const float* __restrict__ llev,
                const float* __restrict__ adW, const float* __restrict__ adb,
                float* __restrict__ wy, float* __restrict__ yhat)
{
  __shared__ __align__(16) ushort smem[SMEM_USHORTS];
  const int bid = blockIdx.x;
  ushort* h3 = h1;   // alias safe (pipeline ordering, see r5 analysis)
  if (bid < 32) {
    lstm_scan<1,0>(smem, xhat, h1, Wih0, Whh_all, bih_all, bhh_all,
                   0, bid, flags, nullptr, nullptr, nullptr, nullptr, nullptr, nullptr, nullptr);
  } else if (bid < 96) {
    lstm_scan<2,1>(smem, h1, h2, Wih_rest, Whh_all + 256*64, bih_all + 256, bhh_all + 256,
                   (bid-32) >> 5, (bid-32) & 31, flags, nullptr, nullptr, nullptr, nullptr, nullptr, nullptr, nullptr);
  } else if (bid < 224) {
    lstm_scan<2,2>(smem, h2, h3, Wih_rest + 256*64, Whh_all + 2*256*64, bih_all + 2*256, bhh_all + 2*256,
                   (bid-96) >> 5, (bid-96) & 31, flags, nullptr, nullptr, nullptr, nullptr, nullptr, nullptr, nullptr);
  } else {
    lstm_scan<2,3>(smem, h3, nullptr, Wih_rest + 2*256*64, Whh_all + 3*256*64, bih_all + 3*256, bhh_all + 3*256,
                   (bid-224) >> 5, (bid-224) & 31, flags, lnorm, llev, adW, adb, h2, wy, yhat);
  }
}

extern "C" void kernel_launch(void* const* d_in, const int* in_sizes, int n_in,
                              void* d_out, int out_size, void* d_ws, size_t ws_size,
                              hipStream_t stream) {
  const float* y         = (const float*)d_in[0];
  const int*   idxs      = (const int*)d_in[1];
  const float* noise     = (const float*)d_in[2];
  const float* lev_sms   = (const float*)d_in[3];
  const float* seas_sms  = (const float*)d_in[4];
  const float* init_seas = (const float*)d_in[5];
  const float* Wih0      = (const float*)d_in[6];
  const float* Wih_rest  = (const float*)d_in[7];
  const float* Whh_all   = (const float*)d_in[8];
  const float* bih_all   = (const float*)d_in[9];
  const float* bhh_all   = (const float*)d_in[10];
  const float* adW       = (const float*)d_in[11];
  const float* adb       = (const float*)d_in[12];

  const size_t NWIN28 = (size_t)T_WIN*512*28;
  const size_t NWIN64 = (size_t)T_WIN*512*64;
  const size_t NYT    = (size_t)NSER*NTIME;
  float* out_wy   = (float*)d_out;
  float* out_yhat = out_wy + NWIN28;
  float* out_lev  = out_yhat + NWIN28;

  int*   flags = (int*)d_ws;                       // 4 KiB reserved
  float* yT    = (float*)((char*)d_ws + 4096);
  float* levT  = yT    + NYT;
  float* seasT = levT  + NYT;
  float* lnorm = seasT + NYT;
  float* llev  = lnorm + NYT;
  ushort* xhat = (ushort*)(llev + NYT);
  ushort* h1   = (ushort*)((char*)xhat + NWIN28*2);
  ushort* h2   = (ushort*)((char*)h1 + NWIN64*2);

  size_t need = 4096 + (size_t)5*NYT*4 + NWIN28*2 + 2*NWIN64*2;
  if (ws_size < need) {
    fprintf(stderr, "kernel_launch: ws_size %zu < needed %zu\n", ws_size, need);
    return;
  }

  hipMemsetAsync(flags, 0, FLAGS_INTS*sizeof(int), stream);
  transpose_y<<<256,256,0,stream>>>(y, yT);
  es_kernel_t<<<8,64,0,stream>>>(yT, idxs, lev_sms, seas_sms, init_seas, levT, seasT);
  trlog_kernel<<<256,256,0,stream>>>(y, levT, seasT, out_lev, lnorm, llev);
  window_kernel<<<2048,256,0,stream>>>(lnorm, llev, noise, xhat);

  lstm_fused<<<480,256,0,stream>>>(xhat, h1, h2, Wih0, Wih_rest, Whh_all,
                                   bih_all, bhh_all, flags,
                                   lnorm, llev, adW, adb, out_wy, out_yhat);
}

// Round 18
// 2623.689 us; speedup vs baseline: 1.2247x; 1.2247x over previous
//
#include <hip/hip_runtime.h>
#include <hip/hip_bf16.h>
#include <cstdio>

typedef __hip_bfloat16 bf16;
typedef __attribute__((ext_vector_type(8))) short short8v;
typedef __attribute__((ext_vector_type(4))) float f32x4;

#define T_WIN 1993      // N_WINDOWS
#define NSER 512
#define NTIME 2048
#define NGRP 32
#define FLAGS_INTS (4*8*NGRP)

#define WAIT_LGKM0 0xC07F   // lgkmcnt(0) only
#define WAIT_VM0   0x0F70   // vmcnt(0) only

#define SMEM_USHORTS 2304   // hbuf: 2 × 16×72 ushorts (4608 B)

__device__ __forceinline__ float sigmf(float x) { return __fdividef(1.f, 1.f + __expf(-x)); }
__device__ __forceinline__ float tanhf_fast(float x) { return 1.f - __fdividef(2.f, __expf(2.f*x) + 1.f); }
__device__ __forceinline__ ushort f2bfu(float f) {
  __hip_bfloat16 h = __float2bfloat16(f);
  return *reinterpret_cast<ushort*>(&h);
}
__device__ __forceinline__ float bfu2f(ushort u) {
  uint x = ((uint)u) << 16;
  return __uint_as_float(x);
}

// ---------------- y[s][t] -> yT[t][s] (LDS-tiled, conflict-free) -----------
__global__ __launch_bounds__(256) void transpose_y(const float* __restrict__ y,
                                                   float* __restrict__ yT) {
  __shared__ float tile[64][65];
  const int i  = threadIdx.x;
  const int c  = i & 63;
  const int r4 = i >> 6;
  const int t0 = (blockIdx.x & 31) * 64;
  const int s0 = (blockIdx.x >> 5) * 64;
  #pragma unroll
  for (int q = 0; q < 16; ++q) {
    const int sl = q*4 + r4;
    tile[c][sl] = y[(size_t)(s0 + sl)*NTIME + t0 + c];
  }
  __syncthreads();
  #pragma unroll
  for (int q = 0; q < 16; ++q) {
    const int tl = q*4 + r4;
    yT[(size_t)(t0 + tl)*NSER + s0 + c] = tile[tl][c];
  }
}

// ------- ES scan: 16-deep register prefetch ring takes the yT load latency
// off the serial chain (was ~500 cyc/iter exposed -> ~400-500 us hidden cost).
// All yreg indices STATIC (full 16-unroll + 15-iter static tail, rule #20).
__global__ __launch_bounds__(64) void es_kernel_t(const float* __restrict__ yT, const int* __restrict__ idxs,
                            const float* __restrict__ lev_sms, const float* __restrict__ seas_sms,
                            const float* __restrict__ init_seas,
                            float* __restrict__ levT, float* __restrict__ seasT) {
  int s = blockIdx.x*64 + threadIdx.x;
  if (s >= NSER) return;
  int id = idxs[s];
  float ls = sigmf(lev_sms[id]);
  float ss = sigmf(seas_sms[id]);
  float buf[8];
  #pragma unroll
  for (int k=0;k<7;++k) buf[k] = __expf(init_seas[id*7+k]);
  buf[7] = buf[0];
  float lev = __fdividef(yT[s], buf[0]);
  levT[s] = lev;
  #pragma unroll
  for (int t=0;t<8;++t) seasT[t*NSER + s] = buf[t];

  float yreg[16];
  #pragma unroll
  for (int q = 0; q < 16; ++q) yreg[q] = yT[(1+q)*NSER + s];   // t = 1..16

  int tb = 1;
  for (; tb + 16 <= NTIME; tb += 16) {     // covers t = 1..2032
    #pragma unroll
    for (int q = 0; q < 16; ++q) {
      const int t = tb + q;
      const float yt = yreg[q];
      const float st = buf[1];
      lev = ls*__fdividef(yt,st) + (1.f-ls)*lev;
      const float ns = ss*__fdividef(yt,lev) + (1.f-ss)*st;
      #pragma unroll
      for (int k=0;k<7;++k) buf[k] = buf[k+1];
      buf[7] = ns;
      levT[t*NSER + s] = lev;
      if (t+7 < NTIME) seasT[(t+7)*NSER + s] = ns;
      int tp = tb + 16 + q;                 // prefetch 16 ahead (clamped)
      if (tp > NTIME-1) tp = NTIME-1;
      yreg[q] = yT[tp*NSER + s];
    }
  }
  // tail: t = 2033..2047 (15 iters), yreg[q] holds t = 2033+q
  #pragma unroll
  for (int q = 0; q < 15; ++q) {
    const int t = NTIME - 15 + q;
    const float yt = yreg[q];
    const float st = buf[1];
    lev = ls*__fdividef(yt,st) + (1.f-ls)*lev;
    const float ns = ss*__fdividef(yt,lev) + (1.f-ss)*st;
    #pragma unroll
    for (int k=0;k<7;++k) buf[k] = buf[k+1];
    buf[7] = ns;
    levT[t*NSER + s] = lev;
    if (t+7 < NTIME) seasT[(t+7)*NSER + s] = ns;
  }
}

// ------- transpose back + fused logs: out_lev/lnorm/llev in [s][t] ---------
__global__ __launch_bounds__(256) void trlog_kernel(const float* __restrict__ y,
        const float* __restrict__ levT, const float* __restrict__ seasT,
        float* __restrict__ out_lev, float* __restrict__ lnorm, float* __restrict__ llev) {
  __shared__ float tl[64][65];
  __shared__ float ts[64][65];
  const int i  = threadIdx.x;
  const int c  = i & 63;
  const int r4 = i >> 6;
  const int t0 = (blockIdx.x & 31) * 64;
  const int s0 = (blockIdx.x >> 5) * 64;
  #pragma unroll
  for (int q = 0; q < 16; ++q) {
    const int tl_ = q*4 + r4;
    const size_t src = (size_t)(t0 + tl_)*NSER + s0 + c;
    tl[tl_][c] = levT[src];
    ts[tl_][c] = seasT[src];
  }
  __syncthreads();
  #pragma unroll
  for (int q = 0; q < 16; ++q) {
    const int sl = q*4 + r4;
    const size_t o = (size_t)(s0 + sl)*NTIME + t0 + c;
    const float lv = tl[c][sl];
    const float sv = ts[c][sl];
    out_lev[o] = lv;
    llev[o]    = __logf(lv);
    lnorm[o]   = __logf(__fdividef(y[o], sv));
  }
}

// ------- windows: grid-stride, 4 elements/thread ---------------------------
__global__ __launch_bounds__(256) void window_kernel(const float* __restrict__ lnorm,
                              const float* __restrict__ llev,
                              const float* __restrict__ noise,
                              float* __restrict__ wy, ushort* __restrict__ xhat) {
  const int NQ = (T_WIN*512*28)/4;
  const int nth = gridDim.x * 256;
  for (int e = blockIdx.x*256 + threadIdx.x; e < NQ; e += nth) {
    const int k4 = (e % 7) * 4;
    const int rs = e / 7;
    const int s  = rs & 511;
    const int w  = rs >> 9;
    const float lv = llev[s*NTIME + 28 + w];
    const float* Ln = lnorm + (size_t)s*NTIME + w + k4;
    const float4 nz = *reinterpret_cast<const float4*>(noise + (size_t)e*4);
    float4 wv;
    wv.x = Ln[28] - lv; wv.y = Ln[29] - lv; wv.z = Ln[30] - lv; wv.w = Ln[31] - lv;
    *reinterpret_cast<float4*>(wy + (size_t)e*4) = wv;
    ushort4 xv;
    xv.x = f2bfu(Ln[0] - lv + 0.001f*nz.x);
    xv.y = f2bfu(Ln[1] - lv + 0.001f*nz.y);
    xv.z = f2bfu(Ln[2] - lv + 0.001f*nz.z);
    xv.w = f2bfu(Ln[3] - lv + 0.001f*nz.w);
    *reinterpret_cast<ushort4*>(xhat + (size_t)e*4) = xv;
  }
}

// ---------------- fused 4-layer pipelined LSTM scan (production, r14) ------
template<int KXS, int LAYER>
__device__ __forceinline__ void lstm_scan(
    ushort* __restrict__ hb,
    const ushort* __restrict__ xin, ushort* __restrict__ hout,
    const float* __restrict__ Wih, const float* __restrict__ Whh,
    const float* __restrict__ bih, const float* __restrict__ bhh,
    const int j, const int g, int* __restrict__ flags)
{
  constexpr int KST  = KXS + 2;
  constexpr int D    = (KXS == 1) ? 28 : 64;
  constexpr int KX   = KXS * 32;
  constexpr int RATE = 1 << LAYER;
  constexpr int SRCR = (LAYER > 0) ? (RATE >> 1) : 1;

  const int i    = threadIdx.x;
  const int lane = i & 63;
  const int wid  = i >> 6;
  const int n15  = lane & 15;
  const int kq   = lane >> 4;
  const int base = g * 16;
  const int wm   = i >> 4;
  const int wu   = (i & 15) * 4;
  const uint km  = (kq == 3) ? 0u : ~0u;

  short8v wfrag[4][KST];
  float bias[4];
  #pragma unroll
  for (int gg = 0; gg < 4; ++gg) {
    const int R = gg*64 + wid*16 + n15;
    bias[gg] = bih[R] + bhh[R];
    #pragma unroll
    for (int kk = 0; kk < KST; ++kk) {
      #pragma unroll
      for (int jj = 0; jj < 8; ++jj) {
        const int k = kk*32 + kq*8 + jj;
        float v;
        if (k < KX) v = (k < D) ? Wih[R*D + k] : 0.f;
        else        v = Whh[R*64 + (k - KX)];
        wfrag[gg][kk][jj] = (short)f2bfu(v);
      }
    }
  }
  f32x4 biasv[4];
  #pragma unroll
  for (int gg = 0; gg < 4; ++gg)
    biasv[gg] = (f32x4){bias[gg], bias[gg], bias[gg], bias[gg]};
  const f32x4 zv = (f32x4){0.f, 0.f, 0.f, 0.f};

  for (int e = i; e < 1152; e += 256) hb[e] = 0;
  __syncthreads();

  const int nsteps = (T_WIN - 1 - j)/RATE + 1;
  const int u = wid*16 + n15;
  float cc[4] = {0.f, 0.f, 0.f, 0.f};

  int* myflag = &flags[(LAYER*8 + j)*NGRP + g];
  int* fp = nullptr;
  int seen0 = 0;
  int prodmax = 0x7fffffff;
  if constexpr (LAYER > 0) {
    const int pp0 = j % SRCR;
    fp = &flags[((LAYER-1)*8 + pp0)*NGRP + g];
    prodmax = (T_WIN - 1 - pp0)/SRCR + 1;
  }

  auto wait_for = [&](int t) __attribute__((always_inline)) {
    if constexpr (LAYER > 0) {
      const int tc = (t < T_WIN) ? t : (T_WIN - 1);
      int need = tc/SRCR + 1;
      need = (need < prodmax) ? need : prodmax;
      if (seen0 >= need) return;
      while (__hip_atomic_load(fp, __ATOMIC_RELAXED, __HIP_MEMORY_SCOPE_AGENT) < need)
        __builtin_amdgcn_s_sleep(8);
      seen0 = __hip_atomic_load(fp, __ATOMIC_ACQUIRE, __HIP_MEMORY_SCOPE_AGENT);
    }
  };

  auto loadx = [&](int t, short8v* xf) __attribute__((always_inline)) {
    const int tc = (t < T_WIN) ? t : (T_WIN - 1);
    const ushort* p = xin + ((size_t)tc*512 + base + n15)*(size_t)D + kq*8;
    if constexpr (D == 64) {
      xf[0] = *reinterpret_cast<const short8v*>(p);
      xf[1] = *reinterpret_cast<const short8v*>(p + 32);
    } else {
      ushort4 a = *reinterpret_cast<const ushort4*>(p);
      ushort4 b = *reinterpret_cast<const ushort4*>(p + 4);
      short8v r;
      r[0]=(short)a.x; r[1]=(short)a.y; r[2]=(short)a.z; r[3]=(short)a.w;
      r[4]=(short)(ushort)(b.x & km); r[5]=(short)(ushort)(b.y & km);
      r[6]=(short)(ushort)(b.z & km); r[7]=(short)(ushort)(b.w & km);
      xf[0] = r;
    }
  };

  auto xmm = [&](const short8v* xf, f32x4* xa) __attribute__((always_inline)) {
    #pragma unroll
    for (int gg = 0; gg < 4; ++gg) {
      f32x4 t = __builtin_amdgcn_mfma_f32_16x16x32_bf16(xf[0], wfrag[gg][0], biasv[gg], 0, 0, 0);
      if constexpr (KXS == 2)
        t = __builtin_amdgcn_mfma_f32_16x16x32_bf16(xf[1], wfrag[gg][1], t, 0, 0, 0);
      xa[gg] = t;
    }
  };

  auto stepc = [&](int S, const f32x4* xaC, f32x4* xaN, short8v* xfN, int tN,
                   uint2* hv, bool doNext) __attribute__((always_inline)) {
    const int p_ = S & 1;
    const ushort* hbp = hb + p_*1152;
    short8v hf0 = *reinterpret_cast<const short8v*>(hbp + n15*72 + kq*8);
    short8v hf1 = *reinterpret_cast<const short8v*>(hbp + n15*72 + 32 + kq*8);
    *hv = *reinterpret_cast<const uint2*>(hbp + wm*72 + wu);
    f32x4 A0 = __builtin_amdgcn_mfma_f32_16x16x32_bf16(hf0, wfrag[0][KXS], xaC[0], 0, 0, 0);
    f32x4 A1 = __builtin_amdgcn_mfma_f32_16x16x32_bf16(hf0, wfrag[1][KXS], xaC[1], 0, 0, 0);
    f32x4 A2 = __builtin_amdgcn_mfma_f32_16x16x32_bf16(hf0, wfrag[2][KXS], xaC[2], 0, 0, 0);
    f32x4 A3 = __builtin_amdgcn_mfma_f32_16x16x32_bf16(hf0, wfrag[3][KXS], xaC[3], 0, 0, 0);
    f32x4 B0 = __builtin_amdgcn_mfma_f32_16x16x32_bf16(hf1, wfrag[0][KXS+1], zv, 0, 0, 0);
    f32x4 B1 = __builtin_amdgcn_mfma_f32_16x16x32_bf16(hf1, wfrag[1][KXS+1], zv, 0, 0, 0);
    f32x4 B2 = __builtin_amdgcn_mfma_f32_16x16x32_bf16(hf1, wfrag[2][KXS+1], zv, 0, 0, 0);
    f32x4 B3 = __builtin_amdgcn_mfma_f32_16x16x32_bf16(hf1, wfrag[3][KXS+1], zv, 0, 0, 0);
    if (doNext) {
      xmm(xfN, xaN);
      loadx(tN, xfN);
    }
    ushort* hbn = hb + (p_^1)*1152;
    #pragma unroll
    for (int r = 0; r < 4; ++r) {
      const float zi = A0[r] + B0[r];
      const float zf = A1[r] + B1[r];
      const float zg = A2[r] + B2[r];
      const float zo = A3[r] + B3[r];
      cc[r] = sigmf(zf)*cc[r] + sigmf(zi)*tanhf_fast(zg);
      const float h_ = sigmf(zo)*tanhf_fast(cc[r]);
      hbn[(kq*4 + r)*72 + u] = f2bfu(h_);
    }
    __builtin_amdgcn_sched_barrier(0);
    __builtin_amdgcn_s_waitcnt(WAIT_LGKM0);
    __builtin_amdgcn_sched_barrier(0);
    __builtin_amdgcn_s_barrier();
  };

  auto sth = [&](int t, uint2 hv) __attribute__((always_inline)) {
    *reinterpret_cast<uint2*>(&hout[((size_t)t*512 + base + wm)*64 + wu]) = hv;
  };

  short8v xf0[KXS], xf1[KXS], xf2[KXS], xf3[KXS];
  f32x4 xaP[4], xaQ[4];
  uint2 hh0, hh1, hh2, hh3;

  wait_for(j + 8*RATE);
  loadx(j, xf0);
  xmm(xf0, xaP);
  loadx(j + 4*RATE, xf0);
  loadx(j +   RATE, xf1);
  loadx(j + 2*RATE, xf2);
  loadx(j + 3*RATE, xf3);

  stepc(0, xaP, xaQ, xf1, j + 5*RATE, &hh0, true);
  stepc(1, xaQ, xaP, xf2, j + 6*RATE, &hh1, true);
  stepc(2, xaP, xaQ, xf3, j + 7*RATE, &hh2, true);
  stepc(3, xaQ, xaP, xf0, j + 8*RATE, &hh3, true);
  sth(j,          hh1);
  sth(j +   RATE, hh2);
  sth(j + 2*RATE, hh3);

  int B = 4;
  for (; B + 4 <= nsteps; B += 4) {
    wait_for(j + (B + 8)*RATE);
    stepc(B+0, xaP, xaQ, xf1, j + (B+5)*RATE, &hh0, true);
    stepc(B+1, xaQ, xaP, xf2, j + (B+6)*RATE, &hh1, true);
    stepc(B+2, xaP, xaQ, xf3, j + (B+7)*RATE, &hh2, true);
    stepc(B+3, xaQ, xaP, xf0, j + (B+8)*RATE, &hh3, true);
    sth(j + (B-1)*RATE, hh0);
    sth(j + (B  )*RATE, hh1);
    sth(j + (B+1)*RATE, hh2);
    sth(j + (B+2)*RATE, hh3);
    if constexpr (LAYER < 3) {
      if ((B & 7) == 4) {
        __builtin_amdgcn_s_waitcnt(WAIT_VM0);
        __builtin_amdgcn_s_barrier();
        if (i == 0)
          __hip_atomic_store(myflag, B+3, __ATOMIC_RELEASE, __HIP_MEMORY_SCOPE_AGENT);
      }
    }
  }
  for (; B < nsteps; ++B) {
    uint2 hvT;
    if (B & 1) stepc(B, xaQ, nullptr, nullptr, 0, &hvT, false);
    else       stepc(B, xaP, nullptr, nullptr, 0, &hvT, false);
    sth(j + (B-1)*RATE, hvT);
  }

  {
    const int pF = nsteps & 1;
    const int tF = j + (nsteps - 1)*RATE;
    uint2 hv = *reinterpret_cast<const uint2*>(hb + pF*1152 + wm*72 + wu);
    sth(tF, hv);
  }
  if constexpr (LAYER < 3) {
    __builtin_amdgcn_s_waitcnt(WAIT_VM0);
    __builtin_amdgcn_s_barrier();
    if (i == 0)
      __hip_atomic_store(myflag, nsteps, __ATOMIC_RELEASE, __HIP_MEMORY_SCOPE_AGENT);
  }
}

__global__ __launch_bounds__(256, 2)
void lstm_fused(const ushort* __restrict__ xhat,
                ushort* __restrict__ h1, ushort* __restrict__ h2, ushort* __restrict__ h4,
                const float* __restrict__ Wih0, const float* __restrict__ Wih_rest,
                const float* __restrict__ Whh_all,
                const float* __restrict__ bih_all, const float* __restrict__ bhh_all,
                int* __restrict__ flags)
{
  __shared__ __align__(16) ushort smem[SMEM_USHORTS];
  const int bid = blockIdx.x;
  ushort* h3 = h1;   // alias safe (pipeline ordering, see r5 analysis)
  if (bid < 32) {
    lstm_scan<1,0>(smem, xhat, h1, Wih0, Whh_all, bih_all, bhh_all,
                   0, bid, flags);
  } else if (bid < 96) {
    lstm_scan<2,1>(smem, h1, h2, Wih_rest, Whh_all + 256*64, bih_all + 256, bhh_all + 256,
                   (bid-32) >> 5, (bid-32) & 31, flags);
  } else if (bid < 224) {
    lstm_scan<2,2>(smem, h2, h3, Wih_rest + 256*64, Whh_all + 2*256*64, bih_all + 2*256, bhh_all + 2*256,
                   (bid-96) >> 5, (bid-96) & 31, flags);
  } else {
    lstm_scan<2,3>(smem, h3, h4, Wih_rest + 2*256*64, Whh_all + 3*256*64, bih_all + 3*256, bhh_all + 3*256,
                   (bid-224) >> 5, (bid-224) & 31, flags);
  }
}

// ------- adapter: grid-stride over 64-row tiles ----------------------------
__global__ __launch_bounds__(256) void adapter_kernel(const ushort* __restrict__ h4, const ushort* __restrict__ h2,
      const float* __restrict__ adW, const float* __restrict__ adb, float* __restrict__ out) {
  __shared__ __align__(16) float xrow[64*64];
  const int i = threadIdx.x;
  const int ntiles = (T_WIN*512)/64;   // 15,944 exactly
  const int o  = i & 31;
  const int rg = i >> 5;
  float w[64]; float bo = 0.f;
  if (o < 28) {
    #pragma unroll
    for (int uu=0;uu<64;++uu) w[uu] = adW[o*64+uu];
    bo = adb[o];
  }
  for (int tile = blockIdx.x; tile < ntiles; tile += gridDim.x) {
    const int base = tile * 64;
    __syncthreads();
    for (int e = i; e < 512; e += 256) {
      const int r  = e >> 3;
      const int c8 = (e & 7) * 8;
      size_t gi = (size_t)(base + r)*64 + c8;
      uint4 a = *reinterpret_cast<const uint4*>(h4 + gi);
      uint4 b = *reinterpret_cast<const uint4*>(h2 + gi);
      const uint* au = &a.x; const uint* bu = &b.x;
      #pragma unroll
      for (int q = 0; q < 4; ++q) {
        uint av = au[q], bv = bu[q];
        xrow[r*64 + c8 + 2*q]     = bfu2f((ushort)(av & 0xFFFF)) + bfu2f((ushort)(bv & 0xFFFF));
        xrow[r*64 + c8 + 2*q + 1] = bfu2f((ushort)(av >> 16))    + bfu2f((ushort)(bv >> 16));
      }
    }
    __syncthreads();
    if (o < 28) {
      #pragma unroll
      for (int rr=0; rr<8; ++rr) {
        int r = rg*8 + rr;
        const float4* xp = (const float4*)(&xrow[r*64]);
        float a0 = bo, a1 = 0.f, a2 = 0.f, a3 = 0.f;
        #pragma unroll
        for (int q=0;q<16;++q) {
          float4 xv = xp[q];
          a0 += w[4*q+0]*xv.x; a1 += w[4*q+1]*xv.y;
          a2 += w[4*q+2]*xv.z; a3 += w[4*q+3]*xv.w;
        }
        out[(size_t)(base+r)*28 + o] = (a0+a1)+(a2+a3);
      }
    }
  }
}

extern "C" void kernel_launch(void* const* d_in, const int* in_sizes, int n_in,
                              void* d_out, int out_size, void* d_ws, size_t ws_size,
                              hipStream_t stream) {
  const float* y         = (const float*)d_in[0];
  const int*   idxs      = (const int*)d_in[1];
  const float* noise     = (const float*)d_in[2];
  const float* lev_sms   = (const float*)d_in[3];
  const float* seas_sms  = (const float*)d_in[4];
  const float* init_seas = (const float*)d_in[5];
  const float* Wih0      = (const float*)d_in[6];
  const float* Wih_rest  = (const float*)d_in[7];
  const float* Whh_all   = (const float*)d_in[8];
  const float* bih_all   = (const float*)d_in[9];
  const float* bhh_all   = (const float*)d_in[10];
  const float* adW       = (const float*)d_in[11];
  const float* adb       = (const float*)d_in[12];

  const size_t NWIN28 = (size_t)T_WIN*512*28;
  const size_t NWIN64 = (size_t)T_WIN*512*64;
  const size_t NYT    = (size_t)NSER*NTIME;
  float* out_wy   = (float*)d_out;
  float* out_yhat = out_wy + NWIN28;
  float* out_lev  = out_yhat + NWIN28;

  int*   flags = (int*)d_ws;                       // 4 KiB reserved
  float* yT    = (float*)((char*)d_ws + 4096);
  float* levT  = yT    + NYT;
  float* seasT = levT  + NYT;
  float* lnorm = seasT + NYT;
  float* llev  = lnorm + NYT;
  ushort* xhat = (ushort*)(llev + NYT);
  ushort* h1   = (ushort*)((char*)xhat + NWIN28*2);
  ushort* h2   = (ushort*)((char*)h1 + NWIN64*2);
  ushort* h4   = (ushort*)((char*)h2 + NWIN64*2);

  size_t need = 4096 + (size_t)5*NYT*4 + NWIN28*2 + 3*NWIN64*2;
  if (ws_size < need) {
    fprintf(stderr, "kernel_launch: ws_size %zu < needed %zu\n", ws_size, need);
    return;
  }

  hipMemsetAsync(flags, 0, FLAGS_INTS*sizeof(int), stream);
  transpose_y<<<256,256,0,stream>>>(y, yT);
  es_kernel_t<<<8,64,0,stream>>>(yT, idxs, lev_sms, seas_sms, init_seas, levT, seasT);
  trlog_kernel<<<256,256,0,stream>>>(y, levT, seasT, out_lev, lnorm, llev);
  window_kernel<<<2048,256,0,stream>>>(lnorm, llev, noise, out_wy, xhat);

  lstm_fused<<<480,256,0,stream>>>(xhat, h1, h2, h4, Wih0, Wih_rest, Whh_all,
                                   bih_all, bhh_all, flags);

  adapter_kernel<<<2048,256,0,stream>>>(h4, h2, adW, adb, out_yhat);
}

// Round 19
// 2386.603 us; speedup vs baseline: 1.3463x; 1.0993x over previous
//
#include <hip/hip_runtime.h>
#include <hip/hip_bf16.h>
#include <cstdio>

typedef __hip_bfloat16 bf16;
typedef __attribute__((ext_vector_type(8))) short short8v;
typedef __attribute__((ext_vector_type(4))) float f32x4;

#define T_WIN 1993      // N_WINDOWS
#define NSER 512
#define NTIME 2048
#define NGRP 32
#define FLAGS_INTS (4*8*NGRP)

#define WAIT_LGKM0 0xC07F   // lgkmcnt(0) only
#define WAIT_VM0   0x0F70   // vmcnt(0) only

#define SMEM_USHORTS 2304   // hbuf: 2 × 16×72 ushorts (4608 B)

__device__ __forceinline__ float sigmf(float x) { return __fdividef(1.f, 1.f + __expf(-x)); }
__device__ __forceinline__ float tanhf_fast(float x) { return 1.f - __fdividef(2.f, __expf(2.f*x) + 1.f); }
// Padé 3/2 tanh, clamped: 1 rcp (trans) + ~6 VALU, vs exp+rcp (2 trans).
// max err ~5e-3 on [-3.6,3.6] ~= bf16 h-quantization noise; gates contract.
__device__ __forceinline__ float tanh_pade(float x) {
  float xc = fminf(fmaxf(x, -3.6f), 3.6f);
  float x2 = xc*xc;
  return xc * (27.f + x2) * __builtin_amdgcn_rcpf(27.f + 9.f*x2);
}
__device__ __forceinline__ float sigp(float x) {
  return 0.5f + 0.5f*tanh_pade(0.5f*x);
}
__device__ __forceinline__ ushort f2bfu(float f) {
  __hip_bfloat16 h = __float2bfloat16(f);
  return *reinterpret_cast<ushort*>(&h);
}
__device__ __forceinline__ float bfu2f(ushort u) {
  uint x = ((uint)u) << 16;
  return __uint_as_float(x);
}

// ---------------- y[s][t] -> yT[t][s] (LDS-tiled, conflict-free) -----------
__global__ __launch_bounds__(256) void transpose_y(const float* __restrict__ y,
                                                   float* __restrict__ yT) {
  __shared__ float tile[64][65];
  const int i  = threadIdx.x;
  const int c  = i & 63;
  const int r4 = i >> 6;
  const int t0 = (blockIdx.x & 31) * 64;
  const int s0 = (blockIdx.x >> 5) * 64;
  #pragma unroll
  for (int q = 0; q < 16; ++q) {
    const int sl = q*4 + r4;
    tile[c][sl] = y[(size_t)(s0 + sl)*NTIME + t0 + c];
  }
  __syncthreads();
  #pragma unroll
  for (int q = 0; q < 16; ++q) {
    const int tl = q*4 + r4;
    yT[(size_t)(t0 + tl)*NSER + s0 + c] = tile[tl][c];
  }
}

// ------- ES scan: 16-deep register prefetch ring (r18 win, kept) -----------
__global__ __launch_bounds__(64) void es_kernel_t(const float* __restrict__ yT, const int* __restrict__ idxs,
                            const float* __restrict__ lev_sms, const float* __restrict__ seas_sms,
                            const float* __restrict__ init_seas,
                            float* __restrict__ levT, float* __restrict__ seasT) {
  int s = blockIdx.x*64 + threadIdx.x;
  if (s >= NSER) return;
  int id = idxs[s];
  float ls = sigmf(lev_sms[id]);
  float ss = sigmf(seas_sms[id]);
  float buf[8];
  #pragma unroll
  for (int k=0;k<7;++k) buf[k] = __expf(init_seas[id*7+k]);
  buf[7] = buf[0];
  float lev = __fdividef(yT[s], buf[0]);
  levT[s] = lev;
  #pragma unroll
  for (int t=0;t<8;++t) seasT[t*NSER + s] = buf[t];

  float yreg[16];
  #pragma unroll
  for (int q = 0; q < 16; ++q) yreg[q] = yT[(1+q)*NSER + s];

  int tb = 1;
  for (; tb + 16 <= NTIME; tb += 16) {
    #pragma unroll
    for (int q = 0; q < 16; ++q) {
      const int t = tb + q;
      const float yt = yreg[q];
      const float st = buf[1];
      lev = ls*__fdividef(yt,st) + (1.f-ls)*lev;
      const float ns = ss*__fdividef(yt,lev) + (1.f-ss)*st;
      #pragma unroll
      for (int k=0;k<7;++k) buf[k] = buf[k+1];
      buf[7] = ns;
      levT[t*NSER + s] = lev;
      if (t+7 < NTIME) seasT[(t+7)*NSER + s] = ns;
      int tp = tb + 16 + q;
      if (tp > NTIME-1) tp = NTIME-1;
      yreg[q] = yT[tp*NSER + s];
    }
  }
  #pragma unroll
  for (int q = 0; q < 15; ++q) {
    const int t = NTIME - 15 + q;
    const float yt = yreg[q];
    const float st = buf[1];
    lev = ls*__fdividef(yt,st) + (1.f-ls)*lev;
    const float ns = ss*__fdividef(yt,lev) + (1.f-ss)*st;
    #pragma unroll
    for (int k=0;k<7;++k) buf[k] = buf[k+1];
    buf[7] = ns;
    levT[t*NSER + s] = lev;
    if (t+7 < NTIME) seasT[(t+7)*NSER + s] = ns;
  }
}

// ------- transpose back + fused logs: out_lev/lnorm/llev in [s][t] ---------
__global__ __launch_bounds__(256) void trlog_kernel(const float* __restrict__ y,
        const float* __restrict__ levT, const float* __restrict__ seasT,
        float* __restrict__ out_lev, float* __restrict__ lnorm, float* __restrict__ llev) {
  __shared__ float tl[64][65];
  __shared__ float ts[64][65];
  const int i  = threadIdx.x;
  const int c  = i & 63;
  const int r4 = i >> 6;
  const int t0 = (blockIdx.x & 31) * 64;
  const int s0 = (blockIdx.x >> 5) * 64;
  #pragma unroll
  for (int q = 0; q < 16; ++q) {
    const int tl_ = q*4 + r4;
    const size_t src = (size_t)(t0 + tl_)*NSER + s0 + c;
    tl[tl_][c] = levT[src];
    ts[tl_][c] = seasT[src];
  }
  __syncthreads();
  #pragma unroll
  for (int q = 0; q < 16; ++q) {
    const int sl = q*4 + r4;
    const size_t o = (size_t)(s0 + sl)*NTIME + t0 + c;
    const float lv = tl[c][sl];
    const float sv = ts[c][sl];
    out_lev[o] = lv;
    llev[o]    = __logf(lv);
    lnorm[o]   = __logf(__fdividef(y[o], sv));
  }
}

// ------- windows: grid-stride, 4 elements/thread ---------------------------
__global__ __launch_bounds__(256) void window_kernel(const float* __restrict__ lnorm,
                              const float* __restrict__ llev,
                              const float* __restrict__ noise,
                              float* __restrict__ wy, ushort* __restrict__ xhat) {
  const int NQ = (T_WIN*512*28)/4;
  const int nth = gridDim.x * 256;
  for (int e = blockIdx.x*256 + threadIdx.x; e < NQ; e += nth) {
    const int k4 = (e % 7) * 4;
    const int rs = e / 7;
    const int s  = rs & 511;
    const int w  = rs >> 9;
    const float lv = llev[s*NTIME + 28 + w];
    const float* Ln = lnorm + (size_t)s*NTIME + w + k4;
    const float4 nz = *reinterpret_cast<const float4*>(noise + (size_t)e*4);
    float4 wv;
    wv.x = Ln[28] - lv; wv.y = Ln[29] - lv; wv.z = Ln[30] - lv; wv.w = Ln[31] - lv;
    *reinterpret_cast<float4*>(wy + (size_t)e*4) = wv;
    ushort4 xv;
    xv.x = f2bfu(Ln[0] - lv + 0.001f*nz.x);
    xv.y = f2bfu(Ln[1] - lv + 0.001f*nz.y);
    xv.z = f2bfu(Ln[2] - lv + 0.001f*nz.z);
    xv.w = f2bfu(Ln[3] - lv + 0.001f*nz.w);
    *reinterpret_cast<ushort4*>(xhat + (size_t)e*4) = xv;
  }
}

// ---------------- fused 4-layer pipelined LSTM scan (production) -----------
// r19: gate phase de-transcendentalized (Padé gates: 20 vs 40 quarter-rate
// trans ops /thread/step) + s_setprio(1) around the compute phase (T5: two
// independent blocks/CU at different phases -> arbitration helps, m191).
template<int KXS, int LAYER>
__device__ __forceinline__ void lstm_scan(
    ushort* __restrict__ hb,
    const ushort* __restrict__ xin, ushort* __restrict__ hout,
    const float* __restrict__ Wih, const float* __restrict__ Whh,
    const float* __restrict__ bih, const float* __restrict__ bhh,
    const int j, const int g, int* __restrict__ flags)
{
  constexpr int KST  = KXS + 2;
  constexpr int D    = (KXS == 1) ? 28 : 64;
  constexpr int KX   = KXS * 32;
  constexpr int RATE = 1 << LAYER;
  constexpr int SRCR = (LAYER > 0) ? (RATE >> 1) : 1;

  const int i    = threadIdx.x;
  const int lane = i & 63;
  const int wid  = i >> 6;
  const int n15  = lane & 15;
  const int kq   = lane >> 4;
  const int base = g * 16;
  const int wm   = i >> 4;
  const int wu   = (i & 15) * 4;
  const uint km  = (kq == 3) ? 0u : ~0u;

  short8v wfrag[4][KST];
  float bias[4];
  #pragma unroll
  for (int gg = 0; gg < 4; ++gg) {
    const int R = gg*64 + wid*16 + n15;
    bias[gg] = bih[R] + bhh[R];
    #pragma unroll
    for (int kk = 0; kk < KST; ++kk) {
      #pragma unroll
      for (int jj = 0; jj < 8; ++jj) {
        const int k = kk*32 + kq*8 + jj;
        float v;
        if (k < KX) v = (k < D) ? Wih[R*D + k] : 0.f;
        else        v = Whh[R*64 + (k - KX)];
        wfrag[gg][kk][jj] = (short)f2bfu(v);
      }
    }
  }
  f32x4 biasv[4];
  #pragma unroll
  for (int gg = 0; gg < 4; ++gg)
    biasv[gg] = (f32x4){bias[gg], bias[gg], bias[gg], bias[gg]};
  const f32x4 zv = (f32x4){0.f, 0.f, 0.f, 0.f};

  for (int e = i; e < 1152; e += 256) hb[e] = 0;
  __syncthreads();

  const int nsteps = (T_WIN - 1 - j)/RATE + 1;
  const int u = wid*16 + n15;
  float cc[4] = {0.f, 0.f, 0.f, 0.f};

  int* myflag = &flags[(LAYER*8 + j)*NGRP + g];
  int* fp = nullptr;
  int seen0 = 0;
  int prodmax = 0x7fffffff;
  if constexpr (LAYER > 0) {
    const int pp0 = j % SRCR;
    fp = &flags[((LAYER-1)*8 + pp0)*NGRP + g];
    prodmax = (T_WIN - 1 - pp0)/SRCR + 1;
  }

  auto wait_for = [&](int t) __attribute__((always_inline)) {
    if constexpr (LAYER > 0) {
      const int tc = (t < T_WIN) ? t : (T_WIN - 1);
      int need = tc/SRCR + 1;
      need = (need < prodmax) ? need : prodmax;
      if (seen0 >= need) return;
      while (__hip_atomic_load(fp, __ATOMIC_RELAXED, __HIP_MEMORY_SCOPE_AGENT) < need)
        __builtin_amdgcn_s_sleep(8);
      seen0 = __hip_atomic_load(fp, __ATOMIC_ACQUIRE, __HIP_MEMORY_SCOPE_AGENT);
    }
  };

  auto loadx = [&](int t, short8v* xf) __attribute__((always_inline)) {
    const int tc = (t < T_WIN) ? t : (T_WIN - 1);
    const ushort* p = xin + ((size_t)tc*512 + base + n15)*(size_t)D + kq*8;
    if constexpr (D == 64) {
      xf[0] = *reinterpret_cast<const short8v*>(p);
      xf[1] = *reinterpret_cast<const short8v*>(p + 32);
    } else {
      ushort4 a = *reinterpret_cast<const ushort4*>(p);
      ushort4 b = *reinterpret_cast<const ushort4*>(p + 4);
      short8v r;
      r[0]=(short)a.x; r[1]=(short)a.y; r[2]=(short)a.z; r[3]=(short)a.w;
      r[4]=(short)(ushort)(b.x & km); r[5]=(short)(ushort)(b.y & km);
      r[6]=(short)(ushort)(b.z & km); r[7]=(short)(ushort)(b.w & km);
      xf[0] = r;
    }
  };

  auto xmm = [&](const short8v* xf, f32x4* xa) __attribute__((always_inline)) {
    #pragma unroll
    for (int gg = 0; gg < 4; ++gg) {
      f32x4 t = __builtin_amdgcn_mfma_f32_16x16x32_bf16(xf[0], wfrag[gg][0], biasv[gg], 0, 0, 0);
      if constexpr (KXS == 2)
        t = __builtin_amdgcn_mfma_f32_16x16x32_bf16(xf[1], wfrag[gg][1], t, 0, 0, 0);
      xa[gg] = t;
    }
  };

  auto stepc = [&](int S, const f32x4* xaC, f32x4* xaN, short8v* xfN, int tN,
                   uint2* hv, bool doNext) __attribute__((always_inline)) {
    const int p_ = S & 1;
    const ushort* hbp = hb + p_*1152;
    __builtin_amdgcn_s_setprio(1);
    short8v hf0 = *reinterpret_cast<const short8v*>(hbp + n15*72 + kq*8);
    short8v hf1 = *reinterpret_cast<const short8v*>(hbp + n15*72 + 32 + kq*8);
    *hv = *reinterpret_cast<const uint2*>(hbp + wm*72 + wu);
    f32x4 A0 = __builtin_amdgcn_mfma_f32_16x16x32_bf16(hf0, wfrag[0][KXS], xaC[0], 0, 0, 0);
    f32x4 A1 = __builtin_amdgcn_mfma_f32_16x16x32_bf16(hf0, wfrag[1][KXS], xaC[1], 0, 0, 0);
    f32x4 A2 = __builtin_amdgcn_mfma_f32_16x16x32_bf16(hf0, wfrag[2][KXS], xaC[2], 0, 0, 0);
    f32x4 A3 = __builtin_amdgcn_mfma_f32_16x16x32_bf16(hf0, wfrag[3][KXS], xaC[3], 0, 0, 0);
    f32x4 B0 = __builtin_amdgcn_mfma_f32_16x16x32_bf16(hf1, wfrag[0][KXS+1], zv, 0, 0, 0);
    f32x4 B1 = __builtin_amdgcn_mfma_f32_16x16x32_bf16(hf1, wfrag[1][KXS+1], zv, 0, 0, 0);
    f32x4 B2 = __builtin_amdgcn_mfma_f32_16x16x32_bf16(hf1, wfrag[2][KXS+1], zv, 0, 0, 0);
    f32x4 B3 = __builtin_amdgcn_mfma_f32_16x16x32_bf16(hf1, wfrag[3][KXS+1], zv, 0, 0, 0);
    if (doNext) {
      xmm(xfN, xaN);
      loadx(tN, xfN);
    }
    ushort* hbn = hb + (p_^1)*1152;
    #pragma unroll
    for (int r = 0; r < 4; ++r) {
      const float zi = A0[r] + B0[r];
      const float zf = A1[r] + B1[r];
      const float zg = A2[r] + B2[r];
      const float zo = A3[r] + B3[r];
      cc[r] = sigp(zf)*cc[r] + sigp(zi)*tanh_pade(zg);
      const float h_ = sigp(zo)*tanh_pade(cc[r]);
      hbn[(kq*4 + r)*72 + u] = f2bfu(h_);
    }
    __builtin_amdgcn_s_setprio(0);
    __builtin_amdgcn_sched_barrier(0);
    __builtin_amdgcn_s_waitcnt(WAIT_LGKM0);
    __builtin_amdgcn_sched_barrier(0);
    __builtin_amdgcn_s_barrier();
  };

  auto sth = [&](int t, uint2 hv) __attribute__((always_inline)) {
    *reinterpret_cast<uint2*>(&hout[((size_t)t*512 + base + wm)*64 + wu]) = hv;
  };

  short8v xf0[KXS], xf1[KXS], xf2[KXS], xf3[KXS];
  f32x4 xaP[4], xaQ[4];
  uint2 hh0, hh1, hh2, hh3;

  wait_for(j + 8*RATE);
  loadx(j, xf0);
  xmm(xf0, xaP);
  loadx(j + 4*RATE, xf0);
  loadx(j +   RATE, xf1);
  loadx(j + 2*RATE, xf2);
  loadx(j + 3*RATE, xf3);

  stepc(0, xaP, xaQ, xf1, j + 5*RATE, &hh0, true);
  stepc(1, xaQ, xaP, xf2, j + 6*RATE, &hh1, true);
  stepc(2, xaP, xaQ, xf3, j + 7*RATE, &hh2, true);
  stepc(3, xaQ, xaP, xf0, j + 8*RATE, &hh3, true);
  sth(j,          hh1);
  sth(j +   RATE, hh2);
  sth(j + 2*RATE, hh3);

  int B = 4;
  for (; B + 4 <= nsteps; B += 4) {
    wait_for(j + (B + 8)*RATE);
    stepc(B+0, xaP, xaQ, xf1, j + (B+5)*RATE, &hh0, true);
    stepc(B+1, xaQ, xaP, xf2, j + (B+6)*RATE, &hh1, true);
    stepc(B+2, xaP, xaQ, xf3, j + (B+7)*RATE, &hh2, true);
    stepc(B+3, xaQ, xaP, xf0, j + (B+8)*RATE, &hh3, true);
    sth(j + (B-1)*RATE, hh0);
    sth(j + (B  )*RATE, hh1);
    sth(j + (B+1)*RATE, hh2);
    sth(j + (B+2)*RATE, hh3);
    if constexpr (LAYER < 3) {
      if ((B & 7) == 4) {
        __builtin_amdgcn_s_waitcnt(WAIT_VM0);
        __builtin_amdgcn_s_barrier();
        if (i == 0)
          __hip_atomic_store(myflag, B+3, __ATOMIC_RELEASE, __HIP_MEMORY_SCOPE_AGENT);
      }
    }
  }
  for (; B < nsteps; ++B) {
    uint2 hvT;
    if (B & 1) stepc(B, xaQ, nullptr, nullptr, 0, &hvT, false);
    else       stepc(B, xaP, nullptr, nullptr, 0, &hvT, false);
    sth(j + (B-1)*RATE, hvT);
  }

  {
    const int pF = nsteps & 1;
    const int tF = j + (nsteps - 1)*RATE;
    uint2 hv = *reinterpret_cast<const uint2*>(hb + pF*1152 + wm*72 + wu);
    sth(tF, hv);
  }
  if constexpr (LAYER < 3) {
    __builtin_amdgcn_s_waitcnt(WAIT_VM0);
    __builtin_amdgcn_s_barrier();
    if (i == 0)
      __hip_atomic_store(myflag, nsteps, __ATOMIC_RELEASE, __HIP_MEMORY_SCOPE_AGENT);
  }
}

__global__ __launch_bounds__(256, 2)
void lstm_fused(const ushort* __restrict__ xhat,
                ushort* __restrict__ h1, ushort* __restrict__ h2, ushort* __restrict__ h4,
                const float* __restrict__ Wih0, const float* __restrict__ Wih_rest,
                const float* __restrict__ Whh_all,
                const float* __restrict__ bih_all, const float* __restrict__ bhh_all,
                int* __restrict__ flags)
{
  __shared__ __align__(16) ushort smem[SMEM_USHORTS];
  const int bid = blockIdx.x;
  ushort* h3 = h1;   // alias safe (pipeline ordering, see r5 analysis)
  if (bid < 32) {
    lstm_scan<1,0>(smem, xhat, h1, Wih0, Whh_all, bih_all, bhh_all,
                   0, bid, flags);
  } else if (bid < 96) {
    lstm_scan<2,1>(smem, h1, h2, Wih_rest, Whh_all + 256*64, bih_all + 256, bhh_all + 256,
                   (bid-32) >> 5, (bid-32) & 31, flags);
  } else if (bid < 224) {
    lstm_scan<2,2>(smem, h2, h3, Wih_rest + 256*64, Whh_all + 2*256*64, bih_all + 2*256, bhh_all + 2*256,
                   (bid-96) >> 5, (bid-96) & 31, flags);
  } else {
    lstm_scan<2,3>(smem, h3, h4, Wih_rest + 2*256*64, Whh_all + 3*256*64, bih_all + 3*256, bhh_all + 3*256,
                   (bid-224) >> 5, (bid-224) & 31, flags);
  }
}

// ------- adapter: grid-stride over 64-row tiles ----------------------------
__global__ __launch_bounds__(256) void adapter_kernel(const ushort* __restrict__ h4, const ushort* __restrict__ h2,
      const float* __restrict__ adW, const float* __restrict__ adb, float* __restrict__ out) {
  __shared__ __align__(16) float xrow[64*64];
  const int i = threadIdx.x;
  const int ntiles = (T_WIN*512)/64;   // 15,944 exactly
  const int o  = i & 31;
  const int rg = i >> 5;
  float w[64]; float bo = 0.f;
  if (o < 28) {
    #pragma unroll
    for (int uu=0;uu<64;++uu) w[uu] = adW[o*64+uu];
    bo = adb[o];
  }
  for (int tile = blockIdx.x; tile < ntiles; tile += gridDim.x) {
    const int base = tile * 64;
    __syncthreads();
    for (int e = i; e < 512; e += 256) {
      const int r  = e >> 3;
      const int c8 = (e & 7) * 8;
      size_t gi = (size_t)(base + r)*64 + c8;
      uint4 a = *reinterpret_cast<const uint4*>(h4 + gi);
      uint4 b = *reinterpret_cast<const uint4*>(h2 + gi);
      const uint* au = &a.x; const uint* bu = &b.x;
      #pragma unroll
      for (int q = 0; q < 4; ++q) {
        uint av = au[q], bv = bu[q];
        xrow[r*64 + c8 + 2*q]     = bfu2f((ushort)(av & 0xFFFF)) + bfu2f((ushort)(bv & 0xFFFF));
        xrow[r*64 + c8 + 2*q + 1] = bfu2f((ushort)(av >> 16))    + bfu2f((ushort)(bv >> 16));
      }
    }
    __syncthreads();
    if (o < 28) {
      #pragma unroll
      for (int rr=0; rr<8; ++rr) {
        int r = rg*8 + rr;
        const float4* xp = (const float4*)(&xrow[r*64]);
        float a0 = bo, a1 = 0.f, a2 = 0.f, a3 = 0.f;
        #pragma unroll
        for (int q=0;q<16;++q) {
          float4 xv = xp[q];
          a0 += w[4*q+0]*xv.x; a1 += w[4*q+1]*xv.y;
          a2 += w[4*q+2]*xv.z; a3 += w[4*q+3]*xv.w;
        }
        out[(size_t)(base+r)*28 + o] = (a0+a1)+(a2+a3);
      }
    }
  }
}

extern "C" void kernel_launch(void* const* d_in, const int* in_sizes, int n_in,
                              void* d_out, int out_size, void* d_ws, size_t ws_size,
                              hipStream_t stream) {
  const float* y         = (const float*)d_in[0];
  const int*   idxs      = (const int*)d_in[1];
  const float* noise     = (const float*)d_in[2];
  const float* lev_sms   = (const float*)d_in[3];
  const float* seas_sms  = (const float*)d_in[4];
  const float* init_seas = (const float*)d_in[5];
  const float* Wih0      = (const float*)d_in[6];
  const float* Wih_rest  = (const float*)d_in[7];
  const float* Whh_all   = (const float*)d_in[8];
  const float* bih_all   = (const float*)d_in[9];
  const float* bhh_all   = (const float*)d_in[10];
  const float* adW       = (const float*)d_in[11];
  const float* adb       = (const float*)d_in[12];

  const size_t NWIN28 = (size_t)T_WIN*512*28;
  const size_t NWIN64 = (size_t)T_WIN*512*64;
  const size_t NYT    = (size_t)NSER*NTIME;
  float* out_wy   = (float*)d_out;
  float* out_yhat = out_wy + NWIN28;
  float* out_lev  = out_yhat + NWIN28;

  int*   flags = (int*)d_ws;                       // 4 KiB reserved
  float* yT    = (float*)((char*)d_ws + 4096);
  float* levT  = yT    + NYT;
  float* seasT = levT  + NYT;
  float* lnorm = seasT + NYT;
  float* llev  = lnorm + NYT;
  ushort* xhat = (ushort*)(llev + NYT);
  ushort* h1   = (ushort*)((char*)xhat + NWIN28*2);
  ushort* h2   = (ushort*)((char*)h1 + NWIN64*2);
  ushort* h4   = (ushort*)((char*)h2 + NWIN64*2);

  size_t need = 4096 + (size_t)5*NYT*4 + NWIN28*2 + 3*NWIN64*2;
  if (ws_size < need) {
    fprintf(stderr, "kernel_launch: ws_size %zu < needed %zu\n", ws_size, need);
    return;
  }

  hipMemsetAsync(flags, 0, FLAGS_INTS*sizeof(int), stream);
  transpose_y<<<256,256,0,stream>>>(y, yT);
  es_kernel_t<<<8,64,0,stream>>>(yT, idxs, lev_sms, seas_sms, init_seas, levT, seasT);
  trlog_kernel<<<256,256,0,stream>>>(y, levT, seasT, out_lev, lnorm, llev);
  window_kernel<<<2048,256,0,stream>>>(lnorm, llev, noise, out_wy, xhat);

  lstm_fused<<<480,256,0,stream>>>(xhat, h1, h2, h4, Wih0, Wih_rest, Whh_all,
                                   bih_all, bhh_all, flags);

  adapter_kernel<<<2048,256,0,stream>>>(h4, h2, adW, adb, out_yhat);
}